// Round 4
// baseline (249.300 us; speedup 1.0000x reference)
//
#include <hip/hip_runtime.h>
#include <stdint.h>

#define H_ 96
#define W_ 96
#define C_ 256
#define O_ 256
#define N_ 2
#define HW_ (H_*W_)          // 9216
#define M_ (N_*HW_)          // 18432
#define GK 2304              // C_*9

typedef __bf16 bf16x8 __attribute__((ext_vector_type(8)));
typedef float f32x4 __attribute__((ext_vector_type(4)));
typedef unsigned short us4 __attribute__((ext_vector_type(4)));

__device__ __forceinline__ unsigned short f2bf(float f) {
  union { float f; unsigned int u; } v; v.f = f;
  unsigned int u = v.u;
  return (unsigned short)((u + 0x7fffu + ((u >> 16) & 1u)) >> 16);
}
__device__ __forceinline__ float bf2f(unsigned short h) {
  union { unsigned int u; float f; } v; v.u = ((unsigned int)h) << 16;
  return v.f;
}

// ---------------- Kernel 1: NCHW fp32 -> NHWC bf16 transpose
__global__ __launch_bounds__(256) void k_transpose(const float* __restrict__ x,
                                                   unsigned short* __restrict__ xt) {
  __shared__ float tile[32][33];
  const int n = blockIdx.z;
  const int c0 = blockIdx.y * 32;
  const int p0 = blockIdx.x * 32;  // hw
  const int tx = threadIdx.x;      // 0..31
  const int ty = threadIdx.y;      // 0..7
  const float* xp = x + (size_t)n * C_ * HW_;
  unsigned short* xtp = xt + (size_t)n * C_ * HW_;
#pragma unroll
  for (int i = 0; i < 32; i += 8)
    tile[ty + i][tx] = xp[(size_t)(c0 + ty + i) * HW_ + p0 + tx];
  __syncthreads();
#pragma unroll
  for (int i = 0; i < 32; i += 8)
    xtp[(size_t)(p0 + ty + i) * C_ + c0 + tx] = f2bf(tile[tx][ty + i]);
}

// ---------------- Kernel 2: weight prep.
// blocks [0,2304): Wp[o][k*256+c] = bf16(w_deform[o][c][k])     (deform GEMM B)
// blocks [2304,2448): w6p[t][j][c] = bf16(offset conv weights), j<6 real, 6..15 zero
__global__ __launch_bounds__(256) void k_prep(const float* __restrict__ w,
                                              const float* __restrict__ w_tm,
                                              const float* __restrict__ w_tr,
                                              unsigned short* __restrict__ wp,
                                              unsigned short* __restrict__ w6p) {
  const int b = blockIdx.x;
  if (b < 2304) {
    int idx = b * 256 + threadIdx.x;
    int o = idx / GK;
    int kk = idx - o * GK;
    int k = kk >> 8;
    int c = kk & 255;
    wp[idx] = f2bf(w[(size_t)(o * C_ + c) * 9 + k]);
  } else {
    int idx = (b - 2304) * 256 + threadIdx.x;  // < 9*16*256 = 36864
    int t = idx >> 12;
    int r = idx & 4095;
    int j = r >> 8;
    int c = r & 255;
    float v = 0.f;
    if (j < 4) v = w_tm[(size_t)(j * C_ + c) * 9 + t];
    else if (j < 6) v = w_tr[(size_t)((j - 4) * C_ + c) * 9 + t];
    w6p[idx] = f2bf(v);
  }
}

// ---------------- Kernel 3: offset convs via MFMA -> absolute sample coords
// One wave per 16-m tile (16|96 so the tile shares h; only lanes 0/15 at image
// edges need x-masking; y-masking is wave-uniform). A-frag: 16B/lane straight
// from L2-resident xt. B-frag: w6p. 9 taps x 8 ksteps = 72 MFMAs into one acc.
__global__ __launch_bounds__(256) void k_offsets(const unsigned short* __restrict__ xt,
                                                 const unsigned short* __restrict__ w6p,
                                                 const float* __restrict__ b_tm,
                                                 const float* __restrict__ b_tr,
                                                 float* __restrict__ coords) {
  __shared__ float sred[4][16][8];
  const int tid = threadIdx.x;
  const int wave = tid >> 6, lane = tid & 63;
  const int col = lane & 15, quad = lane >> 4;
  const int m0 = blockIdx.x * 64 + wave * 16;
  const int n = m0 / HW_;
  const int hw0 = m0 - n * HW_;
  const int h = hw0 / W_;
  const int w0 = hw0 - h * W_;  // multiple of 16

  f32x4 acc = {0.f, 0.f, 0.f, 0.f};
  const bf16x8 zero8 = {};
#pragma unroll
  for (int t = 0; t < 9; t++) {
    const int ty = t / 3, tx = t % 3;
    const int y = h + ty - 1;
    if (y < 0 || y >= H_) continue;  // wave-uniform
    const int xx = w0 + col + tx - 1;
    const bool valid = (xx >= 0) && (xx < W_);
    const int xc = min(max(xx, 0), W_ - 1);
    const unsigned short* arow = xt + (size_t)((n * H_ + y) * W_ + xc) * C_ + quad * 8;
    const unsigned short* brow = w6p + (size_t)(t * 16 + col) * C_ + quad * 8;
#pragma unroll
    for (int ks = 0; ks < 8; ks++) {
      bf16x8 av = *(const bf16x8*)(const void*)(arow + ks * 32);
      if (!valid) av = zero8;
      bf16x8 bv = *(const bf16x8*)(const void*)(brow + ks * 32);
      acc = __builtin_amdgcn_mfma_f32_16x16x32_bf16(av, bv, acc, 0, 0, 0);
    }
  }
  // D: col=lane&15 (=j), row m_local = quad*4+reg
  if (col < 6) {
#pragma unroll
    for (int r = 0; r < 4; r++) sred[wave][quad * 4 + r][col] = acc[r];
  }
  __syncthreads();
  if (lane < 16) {
    const int m = m0 + lane;
    const float* a = sred[wave][lane];
    const float tm0 = a[0] + b_tm[0];
    const float tm1 = a[1] + b_tm[1];
    const float tm2 = a[2] + b_tm[2];
    const float tm3 = a[3] + b_tm[3];
    const float tr0 = a[4] + b_tr[0];
    const float tr1 = a[5] + b_tr[1];
    const int w = w0 + lane;
#pragma unroll
    for (int t = 0; t < 9; t++) {
      const float ry = (float)(t / 3) - 1.f;
      const float rx = (float)(t % 3) - 1.f;
      coords[(size_t)m * 18 + t * 2 + 0] = (float)h + tr0 + tm0 * ry + tm1 * rx;
      coords[(size_t)m * 18 + t * 2 + 1] = (float)w + tr1 + tm2 * ry + tm3 * rx;
    }
  }
}

// ---------------- Kernel 4: FUSED sample + GEMM + BN + residual + ReLU.
// Block: 32m x 128o, 4 waves (wave = 16m x 64o = 1x4 MFMA tiles). Grid 1152.
// A-tile (32 rows x 64 ch) is bilinear-sampled from xt on the fly into
// XOR-swizzled LDS (no Amat round-trip). Bs staged via global_load_lds.
__global__ __launch_bounds__(256, 4) void k_fused(const unsigned short* __restrict__ xt,
                                                  const unsigned short* __restrict__ Wp,
                                                  const float* __restrict__ coords,
                                                  const float* __restrict__ xres,
                                                  const float* __restrict__ gamma,
                                                  const float* __restrict__ beta,
                                                  const float* __restrict__ mean,
                                                  const float* __restrict__ var,
                                                  float* __restrict__ out) {
  __shared__ unsigned short As[32 * 64] __attribute__((aligned(16)));
  __shared__ unsigned short Bs[128 * 64] __attribute__((aligned(16)));
  const int tid = threadIdx.x;
  const int wave = tid >> 6, lane = tid & 63;
  const int row = lane & 15, quad = lane >> 4;
  const int wm = wave & 1, wo = wave >> 1;  // 16-m half, 64-o half
  const int bo = blockIdx.x & 1, bm = blockIdx.x >> 1;
  const int m0 = bm * 32, o0 = bo * 128;
  const int n = m0 / HW_;  // 32 | 9216: tile never crosses n
  const int sr = tid >> 4;  // staging row 0..15 (+16 on pass 1)
  const int cg = tid & 15;  // staging 4-channel group

  f32x4 acc[4] = {};

  for (int k0 = 0; k0 < GK; k0 += 64) {
    const int tap = k0 >> 8;
    const int cb = k0 & 255;  // 0,64,128,192 — never crosses a tap
    // ---- A staging: bilinear sample 32 rows x 64 ch into swizzled LDS
#pragma unroll
    for (int pass = 0; pass < 2; pass++) {
      const int r = pass * 16 + sr;
      const int m = m0 + r;
      const float py = coords[(size_t)m * 18 + tap * 2 + 0];
      const float px = coords[(size_t)m * 18 + tap * 2 + 1];
      const float fy = floorf(py), fx = floorf(px);
      const float wy = py - fy, wx = px - fx;
      const int y0 = (int)fy, x0 = (int)fx;
      const int y1 = y0 + 1, x1 = x0 + 1;
      const float vy0 = (y0 >= 0 && y0 < H_) ? 1.f : 0.f;
      const float vy1 = (y1 >= 0 && y1 < H_) ? 1.f : 0.f;
      const float vx0 = (x0 >= 0 && x0 < W_) ? 1.f : 0.f;
      const float vx1 = (x1 >= 0 && x1 < W_) ? 1.f : 0.f;
      const float w00 = (1.f - wy) * (1.f - wx) * vy0 * vx0;
      const float w01 = (1.f - wy) * wx * vy0 * vx1;
      const float w10 = wy * (1.f - wx) * vy1 * vx0;
      const float w11 = wy * wx * vy1 * vx1;
      const int cy0 = min(max(y0, 0), H_ - 1), cy1 = min(max(y1, 0), H_ - 1);
      const int cx0 = min(max(x0, 0), W_ - 1), cx1 = min(max(x1, 0), W_ - 1);
      const int c4 = cb + cg * 4;
      const us4 u00 = *(const us4*)(xt + (size_t)((n * H_ + cy0) * W_ + cx0) * C_ + c4);
      const us4 u01 = *(const us4*)(xt + (size_t)((n * H_ + cy0) * W_ + cx1) * C_ + c4);
      const us4 u10 = *(const us4*)(xt + (size_t)((n * H_ + cy1) * W_ + cx0) * C_ + c4);
      const us4 u11 = *(const us4*)(xt + (size_t)((n * H_ + cy1) * W_ + cx1) * C_ + c4);
      us4 res;
#pragma unroll
      for (int i = 0; i < 4; i++) {
        float v = w00 * bf2f(u00[i]) + w01 * bf2f(u01[i]) +
                  w10 * bf2f(u10[i]) + w11 * bf2f(u11[i]);
        res[i] = f2bf(v);
      }
      // logical chunk g = cg>>1 (8 bf16), half = cg&1; LDS slot = g ^ (r&7)
      *(us4*)(void*)&As[r * 64 + (((cg >> 1) ^ (r & 7)) << 3) + ((cg & 1) << 2)] = res;
    }
    // ---- B staging: 128 rows x 64 ch = 1024 16B chunks, 4 per thread
#pragma unroll
    for (int i = 0; i < 4; i++) {
      int g = i * 256 + tid;
      int rr = g >> 3, j = g & 7;
      int gc = j ^ (rr & 7);
      __builtin_amdgcn_global_load_lds(
          (const __attribute__((address_space(1))) void*)(Wp + (size_t)(o0 + rr) * GK + k0 + gc * 8),
          (__attribute__((address_space(3))) void*)(&Bs[(size_t)g * 8]),
          16, 0, 0);
    }
    __syncthreads();
#pragma unroll
    for (int ks = 0; ks < 64; ks += 32) {
      const int cbk = ks >> 3;
      const int ra = wm * 16 + row;
      bf16x8 av = *(const bf16x8*)(const void*)&As[ra * 64 + (((cbk + quad) ^ (ra & 7)) << 3)];
#pragma unroll
      for (int ot = 0; ot < 4; ot++) {
        int rb = wo * 64 + ot * 16 + row;
        bf16x8 bv = *(const bf16x8*)(const void*)&Bs[rb * 64 + (((cbk + quad) ^ (rb & 7)) << 3)];
        acc[ot] = __builtin_amdgcn_mfma_f32_16x16x32_bf16(av, bv, acc[ot], 0, 0, 0);
      }
    }
    __syncthreads();
  }

#pragma unroll
  for (int ot = 0; ot < 4; ot++) {
    const int o = o0 + wo * 64 + ot * 16 + row;
    const float sc = rsqrtf(var[o] + 1e-5f) * gamma[o];
    const float bi = beta[o] - mean[o] * sc;
    const size_t obase = (size_t)(n * O_ + o) * HW_;
    const int hwb = m0 - n * HW_ + wm * 16 + quad * 4;
#pragma unroll
    for (int r = 0; r < 4; r++) {
      const int hw = hwb + r;
      const float v = acc[ot][r] * sc + bi + xres[obase + hw];
      out[obase + hw] = fmaxf(v, 0.f);
    }
  }
}

extern "C" void kernel_launch(void* const* d_in, const int* in_sizes, int n_in,
                              void* d_out, int out_size, void* d_ws, size_t ws_size,
                              hipStream_t stream) {
  const float* x     = (const float*)d_in[0];
  const float* w_tm  = (const float*)d_in[2];
  const float* b_tm  = (const float*)d_in[3];
  const float* w_tr  = (const float*)d_in[4];
  const float* b_tr  = (const float*)d_in[5];
  const float* w_df  = (const float*)d_in[6];
  const float* gamma = (const float*)d_in[7];
  const float* beta  = (const float*)d_in[8];
  const float* mean  = (const float*)d_in[9];
  const float* var   = (const float*)d_in[10];
  float* out = (float*)d_out;

  char* ws = (char*)d_ws;
  unsigned short* xt   = (unsigned short*)(ws);                       //  9,437,184 B
  float* coords        = (float*)(ws + 9437184);                      //  1,327,104 B
  unsigned short* WpB  = (unsigned short*)(ws + 9437184 + 1327104);   //  1,179,648 B
  unsigned short* w6p  = (unsigned short*)(ws + 9437184 + 1327104 + 1179648); // 73,728 B

  k_prep<<<2448, 256, 0, stream>>>(w_df, w_tm, w_tr, WpB, w6p);
  k_transpose<<<dim3(HW_ / 32, C_ / 32, N_), dim3(32, 8), 0, stream>>>(x, xt);
  k_offsets<<<M_ / 64, 256, 0, stream>>>(xt, w6p, b_tm, b_tr, coords);
  k_fused<<<(M_ / 32) * 2, 256, 0, stream>>>(xt, WpB, coords, x, gamma, beta, mean, var, out);
}

// Round 5
// 204.381 us; speedup vs baseline: 1.2198x; 1.2198x over previous
//
#include <hip/hip_runtime.h>
#include <stdint.h>

#define H_ 96
#define W_ 96
#define C_ 256
#define O_ 256
#define N_ 2
#define HW_ (H_*W_)          // 9216
#define M_ (N_*HW_)          // 18432
#define GK 2304              // C_*9

typedef __bf16 bf16x8 __attribute__((ext_vector_type(8)));
typedef float f32x4 __attribute__((ext_vector_type(4)));
typedef unsigned short us4 __attribute__((ext_vector_type(4)));

__device__ __forceinline__ unsigned short f2bf(float f) {
  union { float f; unsigned int u; } v; v.f = f;
  unsigned int u = v.u;
  return (unsigned short)((u + 0x7fffu + ((u >> 16) & 1u)) >> 16);
}
__device__ __forceinline__ float bf2f(unsigned short h) {
  union { unsigned int u; float f; } v; v.u = ((unsigned int)h) << 16;
  return v.f;
}

// ---------------- Kernel 1: combined prep.
//  blocks [0,4608):       NCHW fp32 -> NHWC bf16 transpose (32x32 tiles)
//  blocks [4608,4864):    Wp[o][t*256+c] = bf16(w_deform[o][c][t]), one o/block
//  blocks [4864,5008):    w6p[t][j][c] (j<6 real, 6..15 zero)
__global__ __launch_bounds__(256) void k_pre(const float* __restrict__ x,
                                             const float* __restrict__ w_df,
                                             const float* __restrict__ w_tm,
                                             const float* __restrict__ w_tr,
                                             unsigned short* __restrict__ xt,
                                             unsigned short* __restrict__ wp,
                                             unsigned short* __restrict__ w6p) {
  const int b = blockIdx.x;
  const int tid = threadIdx.x;
  if (b < 4608) {
    __shared__ float tile[32][33];
    const int pb = b % 288, cb8 = (b / 288) & 7, n = b / 2304;
    const int p0 = pb * 32, c0 = cb8 * 32;
    const int tx = tid & 31, ty = tid >> 5;  // 32 x 8
    const float* xp = x + (size_t)n * C_ * HW_;
    unsigned short* xtp = xt + (size_t)n * C_ * HW_;
#pragma unroll
    for (int i = 0; i < 32; i += 8)
      tile[ty + i][tx] = xp[(size_t)(c0 + ty + i) * HW_ + p0 + tx];
    __syncthreads();
    const int p = tid >> 3, g = tid & 7;  // 32 p x 8 c-groups
    us4 v;
#pragma unroll
    for (int i = 0; i < 4; i++) v[i] = f2bf(tile[g * 4 + i][p]);
    *(us4*)(xtp + (size_t)(p0 + p) * C_ + c0 + g * 4) = v;
  } else if (b < 4864) {
    __shared__ float lds[9][258];
    const int o = b - 4608;
    const float* src = w_df + (size_t)o * GK;
#pragma unroll
    for (int i = 0; i < 9; i++) {
      int e = tid + i * 256;           // e = c*9 + t
      int c = e / 9, t = e - c * 9;
      lds[t][c] = src[e];
    }
    __syncthreads();
    unsigned short* dst = wp + (size_t)o * GK;
#pragma unroll
    for (int i = 0; i < 9; i++) {
      int j = tid + i * 256;           // j = t*256 + c
      dst[j] = f2bf(lds[j >> 8][j & 255]);
    }
  } else {
    int idx = (b - 4864) * 256 + tid;  // < 9*16*256 = 36864
    int t = idx >> 12;
    int r = idx & 4095;
    int j = r >> 8;
    int c = r & 255;
    float v = 0.f;
    if (j < 4) v = w_tm[(size_t)(j * C_ + c) * 9 + t];
    else if (j < 6) v = w_tr[(size_t)((j - 4) * C_ + c) * 9 + t];
    w6p[idx] = f2bf(v);
  }
}

// ---------------- Kernel 2: FULLY FUSED offsets + sample + GEMM + BN + res + ReLU.
// Block: 32m x 256o (full O), 4 waves; wave = 16m x 128o (1x8 MFMA tiles).
// Grid 576, XCD-swizzled so each XCD's 72 blocks cover a contiguous m-band
// (per-XCD xt footprint ~2.5MB < 4MB L2; perf-only heuristic).
// Prologue: waves 0-1 run the 6-ch offset conv via MFMA for the block's 32 m,
// coords go to LDS. Main loop: A-tile bilinear-sampled on the fly (weights +
// clamped corner addresses cached in registers across the 4 chunks of a tap);
// B staged via global_load_lds; both XOR-chunk-swizzled in LDS.
__global__ __launch_bounds__(256, 2) void k_fused(const unsigned short* __restrict__ xt,
                                                  const unsigned short* __restrict__ Wp,
                                                  const unsigned short* __restrict__ w6p,
                                                  const float* __restrict__ b_tm,
                                                  const float* __restrict__ b_tr,
                                                  const float* __restrict__ xres,
                                                  const float* __restrict__ gamma,
                                                  const float* __restrict__ beta,
                                                  const float* __restrict__ mean,
                                                  const float* __restrict__ var,
                                                  float* __restrict__ out) {
  __shared__ unsigned short As[32 * 64] __attribute__((aligned(16)));
  __shared__ unsigned short Bs[256 * 64] __attribute__((aligned(16)));
  __shared__ float sred[2][16][8];
  __shared__ float coords_s[32][9][2];
  const int tid = threadIdx.x;
  const int wave = tid >> 6, lane = tid & 63;
  const int row = lane & 15, quad = lane >> 4;
  const int wm = wave & 1, wo = wave >> 1;
  const int bm = (blockIdx.x & 7) * 72 + (blockIdx.x >> 3);  // XCD m-band swizzle
  const int m0 = bm * 32;
  const int n = m0 / HW_;  // 32 | 9216: tile never crosses n
  const int sr = tid >> 4;  // staging row 0..15 (+16 on pass 1)
  const int cg = tid & 15;  // staging 4-channel group
  const int coff = cg * 4;

  // ---- Prologue: offset conv (waves 0,1; one 16-m strip each) ----
  if (wave < 2) {
    const int m0w = m0 + wave * 16;
    const int hw0 = m0w - n * HW_;
    const int h = hw0 / W_;
    const int w0 = hw0 - h * W_;  // multiple of 16
    f32x4 oacc = {0.f, 0.f, 0.f, 0.f};
    const bf16x8 zero8 = {};
#pragma unroll
    for (int t = 0; t < 9; t++) {
      const int ty = t / 3, tx = t % 3;
      const int y = h + ty - 1;
      if (y < 0 || y >= H_) continue;  // wave-uniform
      const int xx = w0 + row + tx - 1;
      const bool valid = (xx >= 0) && (xx < W_);
      const int xc = min(max(xx, 0), W_ - 1);
      const unsigned short* arow = xt + (size_t)((n * H_ + y) * W_ + xc) * C_ + quad * 8;
      const unsigned short* brow = w6p + (size_t)(t * 16 + row) * C_ + quad * 8;
#pragma unroll
      for (int ks = 0; ks < 8; ks++) {
        bf16x8 av = *(const bf16x8*)(const void*)(arow + ks * 32);
        if (!valid) av = zero8;
        bf16x8 bv = *(const bf16x8*)(const void*)(brow + ks * 32);
        oacc = __builtin_amdgcn_mfma_f32_16x16x32_bf16(av, bv, oacc, 0, 0, 0);
      }
    }
    if (row < 6) {
#pragma unroll
      for (int r = 0; r < 4; r++) sred[wave][quad * 4 + r][row] = oacc[r];
    }
  }
  __syncthreads();
  if (wave < 2 && lane < 16) {
    const int r = wave * 16 + lane;
    const int hwm = m0 + r - n * HW_;
    const int h = hwm / W_, w = hwm - h * W_;
    const float* a = sred[wave][lane];
    const float tm0 = a[0] + b_tm[0];
    const float tm1 = a[1] + b_tm[1];
    const float tm2 = a[2] + b_tm[2];
    const float tm3 = a[3] + b_tm[3];
    const float tr0 = a[4] + b_tr[0];
    const float tr1 = a[5] + b_tr[1];
#pragma unroll
    for (int t = 0; t < 9; t++) {
      const float ry = (float)(t / 3) - 1.f;
      const float rx = (float)(t % 3) - 1.f;
      coords_s[r][t][0] = (float)h + tr0 + tm0 * ry + tm1 * rx;
      coords_s[r][t][1] = (float)w + tr1 + tm2 * ry + tm3 * rx;
    }
  }
  __syncthreads();

  // ---- Main loop ----
  f32x4 acc[8] = {};
  float cw[2][4];   // cached bilinear weights (validity folded)
  int cbase[2][4];  // cached clamped corner element-offsets into xt

  for (int k0 = 0; k0 < GK; k0 += 64) {
    const int tap = k0 >> 8;
    const int cb = k0 & 255;  // chunk never crosses a tap
    if (cb == 0) {
#pragma unroll
      for (int pass = 0; pass < 2; pass++) {
        const int r = pass * 16 + sr;
        const float py = coords_s[r][tap][0];
        const float px = coords_s[r][tap][1];
        const float fy = floorf(py), fx = floorf(px);
        const float wy = py - fy, wx = px - fx;
        const int y0 = (int)fy, x0 = (int)fx;
        const int y1 = y0 + 1, x1 = x0 + 1;
        const float vy0 = (y0 >= 0 && y0 < H_) ? 1.f : 0.f;
        const float vy1 = (y1 >= 0 && y1 < H_) ? 1.f : 0.f;
        const float vx0 = (x0 >= 0 && x0 < W_) ? 1.f : 0.f;
        const float vx1 = (x1 >= 0 && x1 < W_) ? 1.f : 0.f;
        cw[pass][0] = (1.f - wy) * (1.f - wx) * vy0 * vx0;
        cw[pass][1] = (1.f - wy) * wx * vy0 * vx1;
        cw[pass][2] = wy * (1.f - wx) * vy1 * vx0;
        cw[pass][3] = wy * wx * vy1 * vx1;
        const int cy0 = min(max(y0, 0), H_ - 1), cy1 = min(max(y1, 0), H_ - 1);
        const int cx0 = min(max(x0, 0), W_ - 1), cx1 = min(max(x1, 0), W_ - 1);
        cbase[pass][0] = ((n * H_ + cy0) * W_ + cx0) * C_;
        cbase[pass][1] = ((n * H_ + cy0) * W_ + cx1) * C_;
        cbase[pass][2] = ((n * H_ + cy1) * W_ + cx0) * C_;
        cbase[pass][3] = ((n * H_ + cy1) * W_ + cx1) * C_;
      }
    }
    // A staging: 32 rows x 64 ch bilinear into swizzled LDS
#pragma unroll
    for (int pass = 0; pass < 2; pass++) {
      const int r = pass * 16 + sr;
      const int c4 = cb + coff;
      const us4 u00 = *(const us4*)(xt + cbase[pass][0] + c4);
      const us4 u01 = *(const us4*)(xt + cbase[pass][1] + c4);
      const us4 u10 = *(const us4*)(xt + cbase[pass][2] + c4);
      const us4 u11 = *(const us4*)(xt + cbase[pass][3] + c4);
      us4 res;
#pragma unroll
      for (int i = 0; i < 4; i++) {
        float v = cw[pass][0] * bf2f(u00[i]) + cw[pass][1] * bf2f(u01[i]) +
                  cw[pass][2] * bf2f(u10[i]) + cw[pass][3] * bf2f(u11[i]);
        res[i] = f2bf(v);
      }
      *(us4*)(void*)&As[r * 64 + (((cg >> 1) ^ (r & 7)) << 3) + ((cg & 1) << 2)] = res;
    }
    // B staging: 256 rows x 64 ch = 2048 16B chunks, 8 per thread
#pragma unroll
    for (int i = 0; i < 8; i++) {
      int g = i * 256 + tid;
      int rr = g >> 3, j = g & 7;
      int gc = j ^ (rr & 7);
      __builtin_amdgcn_global_load_lds(
          (const __attribute__((address_space(1))) void*)(Wp + (size_t)rr * GK + k0 + gc * 8),
          (__attribute__((address_space(3))) void*)(&Bs[(size_t)g * 8]),
          16, 0, 0);
    }
    __syncthreads();
#pragma unroll
    for (int ks = 0; ks < 64; ks += 32) {
      const int cbk = ks >> 3;
      const int ra = wm * 16 + row;
      bf16x8 av = *(const bf16x8*)(const void*)&As[ra * 64 + (((cbk + quad) ^ (ra & 7)) << 3)];
#pragma unroll
      for (int ot = 0; ot < 8; ot++) {
        int rb = wo * 128 + ot * 16 + row;
        bf16x8 bv = *(const bf16x8*)(const void*)&Bs[rb * 64 + (((cbk + quad) ^ (rb & 7)) << 3)];
        acc[ot] = __builtin_amdgcn_mfma_f32_16x16x32_bf16(av, bv, acc[ot], 0, 0, 0);
      }
    }
    __syncthreads();
  }

  // ---- Epilogue: BN + residual + ReLU, float4 rows ----
  const int hwb = m0 - n * HW_ + wm * 16 + quad * 4;
#pragma unroll
  for (int ot = 0; ot < 8; ot++) {
    const int o = wo * 128 + ot * 16 + row;
    const float sc = rsqrtf(var[o] + 1e-5f) * gamma[o];
    const float bi = beta[o] - mean[o] * sc;
    const size_t obase = (size_t)(n * O_ + o) * HW_ + hwb;
    const f32x4 rv = *(const f32x4*)(xres + obase);
    f32x4 ov;
#pragma unroll
    for (int r = 0; r < 4; r++) ov[r] = fmaxf(acc[ot][r] * sc + bi + rv[r], 0.f);
    *(f32x4*)(out + obase) = ov;
  }
}

extern "C" void kernel_launch(void* const* d_in, const int* in_sizes, int n_in,
                              void* d_out, int out_size, void* d_ws, size_t ws_size,
                              hipStream_t stream) {
  const float* x     = (const float*)d_in[0];
  const float* w_tm  = (const float*)d_in[2];
  const float* b_tm  = (const float*)d_in[3];
  const float* w_tr  = (const float*)d_in[4];
  const float* b_tr  = (const float*)d_in[5];
  const float* w_df  = (const float*)d_in[6];
  const float* gamma = (const float*)d_in[7];
  const float* beta  = (const float*)d_in[8];
  const float* mean  = (const float*)d_in[9];
  const float* var   = (const float*)d_in[10];
  float* out = (float*)d_out;

  char* ws = (char*)d_ws;
  unsigned short* xt  = (unsigned short*)(ws);                       //  9,437,184 B
  unsigned short* WpB = (unsigned short*)(ws + 9437184);             //  1,179,648 B
  unsigned short* w6p = (unsigned short*)(ws + 9437184 + 1179648);   //     73,728 B

  k_pre<<<5008, 256, 0, stream>>>(x, w_df, w_tm, w_tr, xt, WpB, w6p);
  k_fused<<<M_ / 32, 256, 0, stream>>>(xt, WpB, w6p, b_tm, b_tr, x,
                                       gamma, beta, mean, var, out);
}